// Round 10
// baseline (174.938 us; speedup 1.0000x reference)
//
#include <hip/hip_runtime.h>

#define N_NODES 50000
#define IN_DIM  128
#define OUT_DIM 256
#define N_EDGES 800000
#define BINA_BLOCKS 64     // 12500 edges each -> ~16-edge (64B, full-line) segments
#define EDGES_PER_BINA 12500
#define WCONV_BLOCKS 4     // 32768/(1024*8)
#define N_BUCKETS 782      // 64-node ranges (ceil(50000/64))
#define BUCKET_CAP 1280    // mean 1023, sd ~32 -> +8 sigma margin

typedef short bf16x8 __attribute__((ext_vector_type(8)));   // 8 bf16 = 4 VGPRs
typedef float f32x4  __attribute__((ext_vector_type(4)));   // MFMA acc
typedef unsigned short ushort8_t __attribute__((ext_vector_type(8)));

__device__ __forceinline__ unsigned short f2bf(float f) {
    unsigned u = __float_as_uint(f);
    return (unsigned short)((u + 0x7fffu + ((u >> 16) & 1u)) >> 16);
}
__device__ __forceinline__ float bf2f(unsigned short h) {
    return __uint_as_float(((unsigned)h) << 16);
}
__device__ __forceinline__ float blo(unsigned p) { return __uint_as_float(p << 16); }
__device__ __forceinline__ float bhi(unsigned p) { return __uint_as_float(p & 0xffff0000u); }

// ---- prep: [binA: bucket-bin edges] | [W->split-bf16]  (1024-thread blocks) ----
// pack = (dst&63)<<16 | src   (src < 2^16 since N_NODES=50000, local < 2^6)

__global__ __launch_bounds__(1024) void k_prep(const int* __restrict__ ei,
                                               int* __restrict__ bcnt,
                                               unsigned* __restrict__ bucketed,
                                               const float* __restrict__ W,
                                               unsigned short* __restrict__ Wh,
                                               unsigned short* __restrict__ Wl) {
    __shared__ int hist[N_BUCKETS];
    __shared__ int cursor[N_BUCKETS];
    int b = blockIdx.x, tid = threadIdx.x;
    if (b < BINA_BLOCKS) {
        int base = b * EDGES_PER_BINA;
        for (int t = tid; t < N_BUCKETS; t += 1024) hist[t] = 0;
        __syncthreads();
        for (int e = tid; e < EDGES_PER_BINA; e += 1024) {
            int2 p = *(const int2*)&ei[2 * (base + e)];
            atomicAdd(&hist[p.y >> 6], 1);     // LDS bucket histogram only
        }
        __syncthreads();
        for (int t = tid; t < N_BUCKETS; t += 1024) {
            int cnt = hist[t];
            cursor[t] = t * BUCKET_CAP + (cnt ? atomicAdd(&bcnt[t], cnt) : 0);
        }
        __syncthreads();
        for (int e = tid; e < EDGES_PER_BINA; e += 1024) {
            int2 p = *(const int2*)&ei[2 * (base + e)];
            int bkt = p.y >> 6;
            int pos = atomicAdd(&cursor[bkt], 1);
            if (pos < (bkt + 1) * BUCKET_CAP)  // overflow guard (never fires at +8 sigma)
                bucketed[pos] = ((unsigned)(p.y & 63) << 16) | (unsigned)p.x;
        }
    } else {
        int t = (b - BINA_BLOCKS) * 1024 + tid;
        int base = t * 8;
        float4 a = *(const float4*)&W[base];
        float4 c = *(const float4*)&W[base + 4];
        ushort8_t h, l;
        h[0] = f2bf(a.x); h[1] = f2bf(a.y); h[2] = f2bf(a.z); h[3] = f2bf(a.w);
        h[4] = f2bf(c.x); h[5] = f2bf(c.y); h[6] = f2bf(c.z); h[7] = f2bf(c.w);
        l[0] = f2bf(a.x - bf2f(h[0])); l[1] = f2bf(a.y - bf2f(h[1]));
        l[2] = f2bf(a.z - bf2f(h[2])); l[3] = f2bf(a.w - bf2f(h[3]));
        l[4] = f2bf(c.x - bf2f(h[4])); l[5] = f2bf(c.y - bf2f(h[5]));
        l[6] = f2bf(c.z - bf2f(h[6])); l[7] = f2bf(c.w - bf2f(h[7]));
        *(ushort8_t*)&Wh[base] = h;
        *(ushort8_t*)&Wl[base] = l;
    }
}

// ---- fused degree + scaled x-conversion: bucket b owns nodes [64b, 64b+64) ----
// hist bucket edges -> counts + dinv for these 64 nodes -> xs = bf16(dinv * x).

__global__ __launch_bounds__(512) void k_degxconv(const int* __restrict__ bcnt,
                                                  const unsigned* __restrict__ bucketed,
                                                  const float* __restrict__ x,
                                                  int* __restrict__ counts,
                                                  unsigned short* __restrict__ xs) {
    __shared__ int h[64];
    __shared__ float sdinv[64];
    int b = blockIdx.x, tid = threadIdx.x;
    int node0 = b << 6;
    if (tid < 64) h[tid] = 0;
    __syncthreads();
    int ecnt = bcnt[b]; if (ecnt > BUCKET_CAP) ecnt = BUCKET_CAP;
    const unsigned* bb = bucketed + b * BUCKET_CAP;
    for (int e = tid; e < ecnt; e += 512)
        atomicAdd(&h[bb[e] >> 16], 1);
    __syncthreads();
    if (tid < 64) {
        int n = node0 + tid;
        if (n < N_NODES) counts[n] = h[tid];
        sdinv[tid] = rsqrtf((float)(h[tid] + 1));
    }
    __syncthreads();
    // 64 rows x 128 cols = 1024 ushort8 groups; 512 threads x 2 iters
    #pragma unroll
    for (int it = 0; it < 2; ++it) {
        int g = it * 512 + tid;                // 0..1023
        int nl = g >> 4;                       // local node (16 groups/row)
        int n = node0 + nl;
        if (n < N_NODES) {
            float d = sdinv[nl];
            int base = n * IN_DIM + (g & 15) * 8;
            float4 a = *(const float4*)&x[base];
            float4 c = *(const float4*)&x[base + 4];
            ushort8_t o;
            o[0] = f2bf(d * a.x); o[1] = f2bf(d * a.y);
            o[2] = f2bf(d * a.z); o[3] = f2bf(d * a.w);
            o[4] = f2bf(d * c.x); o[5] = f2bf(d * c.y);
            o[6] = f2bf(d * c.z); o[7] = f2bf(d * c.w);
            *(ushort8_t*)&xs[base] = o;
        }
    }
}

// ---- aggregate: y[i] = di*(xs[i] + sum_s xs[s]) -- weight-free hot loop ----

__global__ __launch_bounds__(512) void k_aggregate(
        const unsigned* __restrict__ xsu, const int* __restrict__ counts,
        const int* __restrict__ bcnt, const unsigned* __restrict__ bucketed,
        unsigned* __restrict__ yh, unsigned* __restrict__ yl) {
    __shared__ int lsrc[BUCKET_CAP];
    __shared__ int ncnt[64], nstart[64], ncur[64];
    int b = blockIdx.x, tid = threadIdx.x;
    int node0 = b << 6;
    if (tid < 64) {                            // wave 0: 64-wide inclusive shfl-scan
        int n = node0 + tid;
        int c = (n < N_NODES) ? counts[n] : 0;
        ncnt[tid] = c;
        int v = c;
        #pragma unroll
        for (int off = 1; off < 64; off <<= 1) {
            int u = __shfl_up(v, off);
            if (tid >= off) v += u;
        }
        nstart[tid] = v;                       // inclusive end
        ncur[tid] = v - c;                     // exclusive start cursor
    }
    __syncthreads();
    int ecnt = bcnt[b]; if (ecnt > BUCKET_CAP) ecnt = BUCKET_CAP;
    const unsigned* bb = bucketed + b * BUCKET_CAP;
    for (int e = tid; e < ecnt; e += 512) {
        unsigned p = bb[e];
        int pos = atomicAdd(&ncur[p >> 16], 1);
        lsrc[pos] = (int)(p & 0xffffu);
    }
    __syncthreads();
    int wv = tid >> 6, lane = tid & 63;
    for (int k = 0; k < 8; ++k) {
        int ln = wv * 8 + k;
        int i = node0 + ln;
        if (i >= N_NODES) break;
        int cnt = ncnt[ln];
        float di = rsqrtf((float)(cnt + 1));
        int end = nstart[ln];
        int start = end - cnt;
        unsigned pself = xsu[i * 64 + lane];
        float sx = blo(pself), sy = bhi(pself);          // self term (xs = di*x)
        for (int e0 = start; e0 < end; e0 += 64) {
            int ne = end - e0; if (ne > 64) ne = 64;
            int s = (lane < ne) ? lsrc[e0 + lane] : 0;
            int t = 0;
            for (; t + 8 <= ne; t += 8) {
                int s0 = __shfl(s, t),     s1 = __shfl(s, t + 1);
                int s2 = __shfl(s, t + 2), s3 = __shfl(s, t + 3);
                int s4 = __shfl(s, t + 4), s5 = __shfl(s, t + 5);
                int s6 = __shfl(s, t + 6), s7 = __shfl(s, t + 7);
                unsigned p0 = xsu[s0 * 64 + lane], p1 = xsu[s1 * 64 + lane];
                unsigned p2 = xsu[s2 * 64 + lane], p3 = xsu[s3 * 64 + lane];
                unsigned p4 = xsu[s4 * 64 + lane], p5 = xsu[s5 * 64 + lane];
                unsigned p6 = xsu[s6 * 64 + lane], p7 = xsu[s7 * 64 + lane];
                sx += blo(p0) + blo(p1) + blo(p2) + blo(p3)
                    + blo(p4) + blo(p5) + blo(p6) + blo(p7);
                sy += bhi(p0) + bhi(p1) + bhi(p2) + bhi(p3)
                    + bhi(p4) + bhi(p5) + bhi(p6) + bhi(p7);
            }
            for (; t < ne; ++t) {
                int st = __shfl(s, t);
                unsigned p = xsu[st * 64 + lane];
                sx += blo(p); sy += bhi(p);
            }
        }
        float vx = di * sx, vy = di * sy;
        unsigned short hx = f2bf(vx), hy = f2bf(vy);
        unsigned short lx = f2bf(vx - bf2f(hx)), ly = f2bf(vy - bf2f(hy));
        yh[i * 64 + lane] = (unsigned)hx | ((unsigned)hy << 16);
        yl[i * 64 + lane] = (unsigned)lx | ((unsigned)ly << 16);
    }
}

// ------- GEMM: out = relu(y @ W^T + b), split-bf16 MFMA, pre-converted inputs -------

#define LDK 136   // LDS K-stride (ushorts): 272B rows -> b128-aligned, bank-uniform frags

__global__ __launch_bounds__(256) void k_gemm(
        const unsigned short* __restrict__ yh, const unsigned short* __restrict__ yl,
        const unsigned short* __restrict__ Wh, const unsigned short* __restrict__ Wl,
        const float* __restrict__ bias, float* __restrict__ out) {
    __shared__ unsigned short Ah[64 * LDK], Al[64 * LDK];
    int tid = threadIdx.x;
    int lane = tid & 63;
    int wv = tid >> 6;
    int jb = blockIdx.x * 64;        // n fastest-varying -> y-tile reuse in L2
    int i0 = blockIdx.y * 64;
    int n0 = wv * 16;
    int rl = lane & 15;              // m (A) / n (B) within 16-tile
    int quad = lane >> 4;

    bf16x8 bh[4], bl[4];
    #pragma unroll
    for (int ks = 0; ks < 4; ++ks) {
        int off = (jb + n0 + rl) * IN_DIM + ks * 32 + quad * 8;
        bh[ks] = *(const bf16x8*)&Wh[off];
        bl[ks] = *(const bf16x8*)&Wl[off];
    }

    #pragma unroll
    for (int it = 0; it < 4; ++it) {
        int g = it * 256 + tid;      // 0..1023
        int r = g >> 4;              // 0..63
        int c8 = g & 15;             // ushort8 chunk along k
        int row = i0 + r; if (row >= N_NODES) row = N_NODES - 1;
        int ga = row * IN_DIM + c8 * 8;
        int la = r * LDK + c8 * 8;
        *(bf16x8*)&Ah[la] = *(const bf16x8*)&yh[ga];
        *(bf16x8*)&Al[la] = *(const bf16x8*)&yl[ga];
    }
    __syncthreads();

    f32x4 acc[4] = {{0.f,0.f,0.f,0.f},{0.f,0.f,0.f,0.f},{0.f,0.f,0.f,0.f},{0.f,0.f,0.f,0.f}};
    #pragma unroll
    for (int ks = 0; ks < 4; ++ks) {
        int koff = ks * 32 + quad * 8;
        #pragma unroll
        for (int mt = 0; mt < 4; ++mt) {
            bf16x8 ah = *(bf16x8*)&Ah[(mt * 16 + rl) * LDK + koff];
            bf16x8 al = *(bf16x8*)&Al[(mt * 16 + rl) * LDK + koff];
            acc[mt] = __builtin_amdgcn_mfma_f32_16x16x32_bf16(ah, bh[ks], acc[mt], 0, 0, 0);
            acc[mt] = __builtin_amdgcn_mfma_f32_16x16x32_bf16(ah, bl[ks], acc[mt], 0, 0, 0);
            acc[mt] = __builtin_amdgcn_mfma_f32_16x16x32_bf16(al, bh[ks], acc[mt], 0, 0, 0);
        }
    }

    float bv = bias[jb + n0 + rl];
    #pragma unroll
    for (int mt = 0; mt < 4; ++mt) {
        #pragma unroll
        for (int r = 0; r < 4; ++r) {
            int row = i0 + mt * 16 + quad * 4 + r;
            if (row < N_NODES) {
                float v = acc[mt][r] + bv;
                out[row * OUT_DIM + jb + n0 + rl] = fmaxf(v, 0.f);
            }
        }
    }
}

// ---------------- launch ----------------

extern "C" void kernel_launch(void* const* d_in, const int* in_sizes, int n_in,
                              void* d_out, int out_size, void* d_ws, size_t ws_size,
                              hipStream_t stream) {
    const float* x  = (const float*)d_in[0];
    const int*   ei = (const int*)d_in[1];
    const float* W  = (const float*)d_in[2];
    const float* b  = (const float*)d_in[3];
    float* out = (float*)d_out;

    char* ws = (char*)d_ws;
    int*            bcnt     = (int*)(ws + 0);                   // 782 ints (memset)
    int*            counts   = (int*)(ws + 4096);                // 50000 ints (k_degxconv writes)
    unsigned*       bucketed = (unsigned*)(ws + 204800);         // 782*1280 u32 (4.0 MB)
    unsigned*       yh       = (unsigned*)(ws + 4208640);        // 12.8 MB
    unsigned*       yl       = (unsigned*)(ws + 17008640);       // 12.8 MB
    unsigned short* xs       = (unsigned short*)(ws + 29808640); // 12.8 MB (bf16 dinv*x)
    unsigned short* Wh       = (unsigned short*)(ws + 42608640); // 64 KB
    unsigned short* Wl       = (unsigned short*)(ws + 42674176); // 64 KB

    hipMemsetAsync(bcnt, 0, N_BUCKETS * sizeof(int), stream);

    k_prep<<<BINA_BLOCKS + WCONV_BLOCKS, 1024, 0, stream>>>(ei, bcnt, bucketed, W, Wh, Wl);
    k_degxconv<<<N_BUCKETS, 512, 0, stream>>>(bcnt, bucketed, x, counts, xs);
    k_aggregate<<<N_BUCKETS, 512, 0, stream>>>((const unsigned*)xs, counts, bcnt,
                                               bucketed, yh, yl);
    dim3 g(OUT_DIM / 64, (N_NODES + 63) / 64);
    k_gemm<<<g, 256, 0, stream>>>((const unsigned short*)yh, (const unsigned short*)yl,
                                  Wh, Wl, b, out);
}

// Round 11
// 168.506 us; speedup vs baseline: 1.0382x; 1.0382x over previous
//
#include <hip/hip_runtime.h>

#define N_NODES 50000
#define IN_DIM  128
#define OUT_DIM 256
#define N_EDGES 800000
#define BINA_BLOCKS 128    // 6250 edges each (R9 config; 64 regressed prep)
#define EDGES_PER_BINA 6250
#define WCONV_BLOCKS 4     // 32768/(1024*8)
#define N_BUCKETS 782      // 64-node ranges (ceil(50000/64))
#define BUCKET_CAP 1280    // mean 1023, sd ~32 -> +8 sigma margin

typedef short bf16x8 __attribute__((ext_vector_type(8)));   // 8 bf16 = 4 VGPRs
typedef float f32x4  __attribute__((ext_vector_type(4)));   // MFMA acc
typedef unsigned short ushort8_t __attribute__((ext_vector_type(8)));

__device__ __forceinline__ unsigned short f2bf(float f) {
    unsigned u = __float_as_uint(f);
    return (unsigned short)((u + 0x7fffu + ((u >> 16) & 1u)) >> 16);
}
__device__ __forceinline__ float bf2f(unsigned short h) {
    return __uint_as_float(((unsigned)h) << 16);
}
__device__ __forceinline__ float blo(unsigned p) { return __uint_as_float(p << 16); }
__device__ __forceinline__ float bhi(unsigned p) { return __uint_as_float(p & 0xffff0000u); }

// ---- prep: [binA: bucket-bin edges] | [W->split-bf16]  (1024-thread blocks) ----
// pack = (dst&63)<<16 | src   (src < 2^16 since N_NODES=50000, local < 2^6)

__global__ __launch_bounds__(1024) void k_prep(const int* __restrict__ ei,
                                               int* __restrict__ bcnt,
                                               unsigned* __restrict__ bucketed,
                                               const float* __restrict__ W,
                                               unsigned short* __restrict__ Wh,
                                               unsigned short* __restrict__ Wl) {
    __shared__ int hist[N_BUCKETS];
    __shared__ int cursor[N_BUCKETS];
    int b = blockIdx.x, tid = threadIdx.x;
    if (b < BINA_BLOCKS) {
        int base = b * EDGES_PER_BINA;
        for (int t = tid; t < N_BUCKETS; t += 1024) hist[t] = 0;
        __syncthreads();
        for (int e = tid; e < EDGES_PER_BINA; e += 1024) {
            int2 p = *(const int2*)&ei[2 * (base + e)];
            atomicAdd(&hist[p.y >> 6], 1);     // LDS bucket histogram only
        }
        __syncthreads();
        for (int t = tid; t < N_BUCKETS; t += 1024) {
            int cnt = hist[t];
            cursor[t] = t * BUCKET_CAP + (cnt ? atomicAdd(&bcnt[t], cnt) : 0);
        }
        __syncthreads();
        for (int e = tid; e < EDGES_PER_BINA; e += 1024) {
            int2 p = *(const int2*)&ei[2 * (base + e)];
            int bkt = p.y >> 6;
            int pos = atomicAdd(&cursor[bkt], 1);
            if (pos < (bkt + 1) * BUCKET_CAP)  // overflow guard (never fires at +8 sigma)
                bucketed[pos] = ((unsigned)(p.y & 63) << 16) | (unsigned)p.x;
        }
    } else {
        int t = (b - BINA_BLOCKS) * 1024 + tid;
        int base = t * 8;
        float4 a = *(const float4*)&W[base];
        float4 c = *(const float4*)&W[base + 4];
        ushort8_t h, l;
        h[0] = f2bf(a.x); h[1] = f2bf(a.y); h[2] = f2bf(a.z); h[3] = f2bf(a.w);
        h[4] = f2bf(c.x); h[5] = f2bf(c.y); h[6] = f2bf(c.z); h[7] = f2bf(c.w);
        l[0] = f2bf(a.x - bf2f(h[0])); l[1] = f2bf(a.y - bf2f(h[1]));
        l[2] = f2bf(a.z - bf2f(h[2])); l[3] = f2bf(a.w - bf2f(h[3]));
        l[4] = f2bf(c.x - bf2f(h[4])); l[5] = f2bf(c.y - bf2f(h[5]));
        l[6] = f2bf(c.z - bf2f(h[6])); l[7] = f2bf(c.w - bf2f(h[7]));
        *(ushort8_t*)&Wh[base] = h;
        *(ushort8_t*)&Wl[base] = l;
    }
}

// ---- fused degree + scaled x-conversion: bucket b owns nodes [64b, 64b+64) ----

__global__ __launch_bounds__(512) void k_degxconv(const int* __restrict__ bcnt,
                                                  const unsigned* __restrict__ bucketed,
                                                  const float* __restrict__ x,
                                                  int* __restrict__ counts,
                                                  unsigned short* __restrict__ xs) {
    __shared__ int h[64];
    __shared__ float sdinv[64];
    int b = blockIdx.x, tid = threadIdx.x;
    int node0 = b << 6;
    if (tid < 64) h[tid] = 0;
    __syncthreads();
    int ecnt = bcnt[b]; if (ecnt > BUCKET_CAP) ecnt = BUCKET_CAP;
    const unsigned* bb = bucketed + b * BUCKET_CAP;
    for (int e = tid; e < ecnt; e += 512)
        atomicAdd(&h[bb[e] >> 16], 1);
    __syncthreads();
    if (tid < 64) {
        int n = node0 + tid;
        if (n < N_NODES) counts[n] = h[tid];
        sdinv[tid] = rsqrtf((float)(h[tid] + 1));
    }
    __syncthreads();
    #pragma unroll
    for (int it = 0; it < 2; ++it) {
        int g = it * 512 + tid;                // 0..1023
        int nl = g >> 4;                       // local node (16 groups/row)
        int n = node0 + nl;
        if (n < N_NODES) {
            float d = sdinv[nl];
            int base = n * IN_DIM + (g & 15) * 8;
            float4 a = *(const float4*)&x[base];
            float4 c = *(const float4*)&x[base + 4];
            ushort8_t o;
            o[0] = f2bf(d * a.x); o[1] = f2bf(d * a.y);
            o[2] = f2bf(d * a.z); o[3] = f2bf(d * a.w);
            o[4] = f2bf(d * c.x); o[5] = f2bf(d * c.y);
            o[6] = f2bf(d * c.z); o[7] = f2bf(d * c.w);
            *(ushort8_t*)&xs[base] = o;
        }
    }
}

// ---- aggregate: y[i] = di*(xs[i] + sum_s xs[s]) -- 2 edges/wave, uint2 lanes ----
// Lanes 0-31 process even edges, 32-63 odd edges; lane covers cols 4c..4c+3.
// Halves merged with shfl_xor(32) per node.

__global__ __launch_bounds__(512) void k_aggregate(
        const uint2* __restrict__ xs2, const int* __restrict__ counts,
        const int* __restrict__ bcnt, const unsigned* __restrict__ bucketed,
        uint2* __restrict__ yh2, uint2* __restrict__ yl2) {
    __shared__ int lsrc[BUCKET_CAP];
    __shared__ int ncnt[64], nstart[64], ncur[64];
    int b = blockIdx.x, tid = threadIdx.x;
    int node0 = b << 6;
    if (tid < 64) {                            // wave 0: 64-wide inclusive shfl-scan
        int n = node0 + tid;
        int c = (n < N_NODES) ? counts[n] : 0;
        ncnt[tid] = c;
        int v = c;
        #pragma unroll
        for (int off = 1; off < 64; off <<= 1) {
            int u = __shfl_up(v, off);
            if (tid >= off) v += u;
        }
        nstart[tid] = v;                       // inclusive end
        ncur[tid] = v - c;                     // exclusive start cursor
    }
    __syncthreads();
    int ecnt = bcnt[b]; if (ecnt > BUCKET_CAP) ecnt = BUCKET_CAP;
    const unsigned* bb = bucketed + b * BUCKET_CAP;
    for (int e = tid; e < ecnt; e += 512) {
        unsigned p = bb[e];
        int pos = atomicAdd(&ncur[p >> 16], 1);
        lsrc[pos] = (int)(p & 0xffffu);
    }
    __syncthreads();
    int wv = tid >> 6, lane = tid & 63;
    int hh = lane >> 5;                        // edge-parity half
    int c = lane & 31;                         // uint2 col index (cols 4c..4c+3)
    for (int k = 0; k < 8; ++k) {
        int ln = wv * 8 + k;
        int i = node0 + ln;
        if (i >= N_NODES) break;
        int cnt = ncnt[ln];
        float di = rsqrtf((float)(cnt + 1));
        int end = nstart[ln];
        int start = end - cnt;
        float f0 = 0.f, f1 = 0.f, f2 = 0.f, f3 = 0.f;
        if (hh == 0) {                         // self term on lower half
            uint2 p = xs2[i * 32 + c];
            f0 = blo(p.x); f1 = bhi(p.x); f2 = blo(p.y); f3 = bhi(p.y);
        }
        for (int e0 = start; e0 < end; e0 += 64) {
            int ne = end - e0; if (ne > 64) ne = 64;
            int sv = (lane < ne) ? lsrc[e0 + lane] : 0;
            int pairs = ne >> 1;
            int t = 0;
            for (; t + 4 <= pairs; t += 4) {
                int s0 = __shfl(sv, 2 * t + hh);
                int s1 = __shfl(sv, 2 * t + 2 + hh);
                int s2 = __shfl(sv, 2 * t + 4 + hh);
                int s3 = __shfl(sv, 2 * t + 6 + hh);
                uint2 p0 = xs2[s0 * 32 + c];
                uint2 p1 = xs2[s1 * 32 + c];
                uint2 p2 = xs2[s2 * 32 + c];
                uint2 p3 = xs2[s3 * 32 + c];
                f0 += blo(p0.x) + blo(p1.x) + blo(p2.x) + blo(p3.x);
                f1 += bhi(p0.x) + bhi(p1.x) + bhi(p2.x) + bhi(p3.x);
                f2 += blo(p0.y) + blo(p1.y) + blo(p2.y) + blo(p3.y);
                f3 += bhi(p0.y) + bhi(p1.y) + bhi(p2.y) + bhi(p3.y);
            }
            for (; t < pairs; ++t) {
                int s = __shfl(sv, 2 * t + hh);
                uint2 p = xs2[s * 32 + c];
                f0 += blo(p.x); f1 += bhi(p.x); f2 += blo(p.y); f3 += bhi(p.y);
            }
            if (ne & 1) {                      // leftover odd edge -> lower half only
                int s = __shfl(sv, ne - 1);
                if (hh == 0) {
                    uint2 p = xs2[s * 32 + c];
                    f0 += blo(p.x); f1 += bhi(p.x); f2 += blo(p.y); f3 += bhi(p.y);
                }
            }
        }
        f0 += __shfl_xor(f0, 32);
        f1 += __shfl_xor(f1, 32);
        f2 += __shfl_xor(f2, 32);
        f3 += __shfl_xor(f3, 32);
        if (hh == 0) {
            float v0 = di * f0, v1 = di * f1, v2 = di * f2, v3 = di * f3;
            unsigned short h0 = f2bf(v0), h1 = f2bf(v1);
            unsigned short h2 = f2bf(v2), h3 = f2bf(v3);
            uint2 oh, ol;
            oh.x = (unsigned)h0 | ((unsigned)h1 << 16);
            oh.y = (unsigned)h2 | ((unsigned)h3 << 16);
            ol.x = (unsigned)f2bf(v0 - bf2f(h0)) | ((unsigned)f2bf(v1 - bf2f(h1)) << 16);
            ol.y = (unsigned)f2bf(v2 - bf2f(h2)) | ((unsigned)f2bf(v3 - bf2f(h3)) << 16);
            yh2[i * 32 + c] = oh;
            yl2[i * 32 + c] = ol;
        }
    }
}

// ------- GEMM: out = relu(y @ W^T + b), split-bf16 MFMA, pre-converted inputs -------

#define LDK 136   // LDS K-stride (ushorts): 272B rows -> b128-aligned, bank-uniform frags

__global__ __launch_bounds__(256) void k_gemm(
        const unsigned short* __restrict__ yh, const unsigned short* __restrict__ yl,
        const unsigned short* __restrict__ Wh, const unsigned short* __restrict__ Wl,
        const float* __restrict__ bias, float* __restrict__ out) {
    __shared__ unsigned short Ah[64 * LDK], Al[64 * LDK];
    int tid = threadIdx.x;
    int lane = tid & 63;
    int wv = tid >> 6;
    int jb = blockIdx.x * 64;        // n fastest-varying -> y-tile reuse in L2
    int i0 = blockIdx.y * 64;
    int n0 = wv * 16;
    int rl = lane & 15;              // m (A) / n (B) within 16-tile
    int quad = lane >> 4;

    bf16x8 bh[4], bl[4];
    #pragma unroll
    for (int ks = 0; ks < 4; ++ks) {
        int off = (jb + n0 + rl) * IN_DIM + ks * 32 + quad * 8;
        bh[ks] = *(const bf16x8*)&Wh[off];
        bl[ks] = *(const bf16x8*)&Wl[off];
    }

    #pragma unroll
    for (int it = 0; it < 4; ++it) {
        int g = it * 256 + tid;      // 0..1023
        int r = g >> 4;              // 0..63
        int c8 = g & 15;             // ushort8 chunk along k
        int row = i0 + r; if (row >= N_NODES) row = N_NODES - 1;
        int ga = row * IN_DIM + c8 * 8;
        int la = r * LDK + c8 * 8;
        *(bf16x8*)&Ah[la] = *(const bf16x8*)&yh[ga];
        *(bf16x8*)&Al[la] = *(const bf16x8*)&yl[ga];
    }
    __syncthreads();

    f32x4 acc[4] = {{0.f,0.f,0.f,0.f},{0.f,0.f,0.f,0.f},{0.f,0.f,0.f,0.f},{0.f,0.f,0.f,0.f}};
    #pragma unroll
    for (int ks = 0; ks < 4; ++ks) {
        int koff = ks * 32 + quad * 8;
        #pragma unroll
        for (int mt = 0; mt < 4; ++mt) {
            bf16x8 ah = *(bf16x8*)&Ah[(mt * 16 + rl) * LDK + koff];
            bf16x8 al = *(bf16x8*)&Al[(mt * 16 + rl) * LDK + koff];
            acc[mt] = __builtin_amdgcn_mfma_f32_16x16x32_bf16(ah, bh[ks], acc[mt], 0, 0, 0);
            acc[mt] = __builtin_amdgcn_mfma_f32_16x16x32_bf16(ah, bl[ks], acc[mt], 0, 0, 0);
            acc[mt] = __builtin_amdgcn_mfma_f32_16x16x32_bf16(al, bh[ks], acc[mt], 0, 0, 0);
        }
    }

    float bv = bias[jb + n0 + rl];
    #pragma unroll
    for (int mt = 0; mt < 4; ++mt) {
        #pragma unroll
        for (int r = 0; r < 4; ++r) {
            int row = i0 + mt * 16 + quad * 4 + r;
            if (row < N_NODES) {
                float v = acc[mt][r] + bv;
                out[row * OUT_DIM + jb + n0 + rl] = fmaxf(v, 0.f);
            }
        }
    }
}

// ---------------- launch ----------------

extern "C" void kernel_launch(void* const* d_in, const int* in_sizes, int n_in,
                              void* d_out, int out_size, void* d_ws, size_t ws_size,
                              hipStream_t stream) {
    const float* x  = (const float*)d_in[0];
    const int*   ei = (const int*)d_in[1];
    const float* W  = (const float*)d_in[2];
    const float* b  = (const float*)d_in[3];
    float* out = (float*)d_out;

    char* ws = (char*)d_ws;
    int*            bcnt     = (int*)(ws + 0);                   // 782 ints (memset)
    int*            counts   = (int*)(ws + 4096);                // 50000 ints (k_degxconv writes)
    unsigned*       bucketed = (unsigned*)(ws + 204800);         // 782*1280 u32 (4.0 MB)
    unsigned*       yh       = (unsigned*)(ws + 4208640);        // 12.8 MB
    unsigned*       yl       = (unsigned*)(ws + 17008640);       // 12.8 MB
    unsigned short* xs       = (unsigned short*)(ws + 29808640); // 12.8 MB (bf16 dinv*x)
    unsigned short* Wh       = (unsigned short*)(ws + 42608640); // 64 KB
    unsigned short* Wl       = (unsigned short*)(ws + 42674176); // 64 KB

    hipMemsetAsync(bcnt, 0, N_BUCKETS * sizeof(int), stream);

    k_prep<<<BINA_BLOCKS + WCONV_BLOCKS, 1024, 0, stream>>>(ei, bcnt, bucketed, W, Wh, Wl);
    k_degxconv<<<N_BUCKETS, 512, 0, stream>>>(bcnt, bucketed, x, counts, xs);
    k_aggregate<<<N_BUCKETS, 512, 0, stream>>>((const uint2*)xs, counts, bcnt,
                                               bucketed, (uint2*)yh, (uint2*)yl);
    dim3 g(OUT_DIM / 64, (N_NODES + 63) / 64);
    k_gemm<<<g, 256, 0, stream>>>((const unsigned short*)yh, (const unsigned short*)yl,
                                  Wh, Wl, b, out);
}